// Round 9
// baseline (483.281 us; speedup 1.0000x reference)
//
#include <hip/hip_runtime.h>
#include <math.h>

#define D 128
#define BSHIFT 9              // bucket = 512 nodes
#define BCAP 12288            // LDS staging capacity (edges) per bucket

typedef __attribute__((ext_vector_type(8))) _Float16 half8;
typedef __attribute__((ext_vector_type(4))) float floatx4;

// ---------------- threefry2x32 (JAX-compatible, 20 rounds) ----------------
__host__ __device__ __forceinline__ unsigned rotl32(unsigned v, int r) {
  return (v << r) | (v >> (32 - r));
}

__host__ __device__ __forceinline__ void threefry2x32(unsigned k0, unsigned k1,
                                                      unsigned x0, unsigned x1,
                                                      unsigned &o0, unsigned &o1) {
  unsigned ks2 = k0 ^ k1 ^ 0x1BD11BDAu;
  unsigned v0 = x0 + k0;
  unsigned v1 = x1 + k1;
  v0 += v1; v1 = rotl32(v1, 13); v1 ^= v0;
  v0 += v1; v1 = rotl32(v1, 15); v1 ^= v0;
  v0 += v1; v1 = rotl32(v1, 26); v1 ^= v0;
  v0 += v1; v1 = rotl32(v1, 6);  v1 ^= v0;
  v0 += k1; v1 += ks2 + 1u;
  v0 += v1; v1 = rotl32(v1, 17); v1 ^= v0;
  v0 += v1; v1 = rotl32(v1, 29); v1 ^= v0;
  v0 += v1; v1 = rotl32(v1, 16); v1 ^= v0;
  v0 += v1; v1 = rotl32(v1, 24); v1 ^= v0;
  v0 += ks2; v1 += k0 + 2u;
  v0 += v1; v1 = rotl32(v1, 13); v1 ^= v0;
  v0 += v1; v1 = rotl32(v1, 15); v1 ^= v0;
  v0 += v1; v1 = rotl32(v1, 26); v1 ^= v0;
  v0 += v1; v1 = rotl32(v1, 6);  v1 ^= v0;
  v0 += k0; v1 += k1 + 3u;
  v0 += v1; v1 = rotl32(v1, 17); v1 ^= v0;
  v0 += v1; v1 = rotl32(v1, 29); v1 ^= v0;
  v0 += v1; v1 = rotl32(v1, 16); v1 ^= v0;
  v0 += v1; v1 = rotl32(v1, 24); v1 ^= v0;
  v0 += k1; v1 += ks2 + 4u;
  v0 += v1; v1 = rotl32(v1, 13); v1 ^= v0;
  v0 += v1; v1 = rotl32(v1, 15); v1 ^= v0;
  v0 += v1; v1 = rotl32(v1, 26); v1 ^= v0;
  v0 += v1; v1 = rotl32(v1, 6);  v1 ^= v0;
  v0 += ks2; v1 += k0 + 5u;
  o0 = v0; o1 = v1;
}

// float -> fp16 bits (RNE via v_cvt_f16_f32)
__device__ __forceinline__ unsigned short f2h(float f) {
  _Float16 h = (_Float16)f;
  return *(unsigned short*)&h;
}

// packed fp16 max (VOP3P, 1 instr for 2 elements)
__device__ __forceinline__ unsigned pkmax(unsigned a, unsigned b) {
  unsigned r;
  asm("v_pk_max_f16 %0, %1, %2" : "=v"(r) : "v"(a), "v"(b));
  return r;
}

// ================= CSR build (bucket-local, no global per-node atomics) ====

__global__ __launch_bounds__(256) void bucket_count_kernel(
    const int* __restrict__ dst, int* __restrict__ bucketTotal, int nEdges) {
  __shared__ int lc[256];
  int t = threadIdx.x;
  lc[t] = 0;
  __syncthreads();
  int e0 = blockIdx.x * 4096;
  for (int i = t; i < 4096; i += 256) {
    int e = e0 + i;
    if (e < nEdges) atomicAdd(&lc[dst[e] >> BSHIFT], 1);
  }
  __syncthreads();
  int c = lc[t];
  if (c > 0) atomicAdd(&bucketTotal[t], c);
}

__global__ __launch_bounds__(256) void scan_buckets_kernel(
    const int* __restrict__ bucketTotal, int* __restrict__ buckOff,
    int* __restrict__ bucketCursor, int nBuck) {
  __shared__ int s[256];
  int t = threadIdx.x;
  int v = (t < nBuck) ? bucketTotal[t] : 0;
  s[t] = v;
  __syncthreads();
  for (int off = 1; off < 256; off <<= 1) {
    int u = (t >= off) ? s[t - off] : 0;
    __syncthreads();
    s[t] += u;
    __syncthreads();
  }
  int excl = s[t] - v;
  if (t < nBuck) {
    buckOff[t] = excl;
    bucketCursor[t] = excl;
  } else if (t == nBuck) {
    buckOff[t] = s[255];  // total edge count
  }
}

// pairs entry packed: (src << 9) | (dst & 511)  — src < 2^17, fits 26 bits.
__global__ __launch_bounds__(256) void bucket_scatter_kernel(
    const int* __restrict__ src, const int* __restrict__ dst,
    int* __restrict__ bucketCursor, unsigned* __restrict__ pairs,
    int nEdges, int nBuck) {
  __shared__ int lcount[256];
  __shared__ int lbase[256];
  __shared__ int loff[256];
  int t = threadIdx.x;
  lcount[t] = 0; loff[t] = 0;
  __syncthreads();
  int e0 = blockIdx.x * 4096;
  for (int i = t; i < 4096; i += 256) {
    int e = e0 + i;
    if (e < nEdges) atomicAdd(&lcount[dst[e] >> BSHIFT], 1);
  }
  __syncthreads();
  if (t < nBuck) {
    int c = lcount[t];
    if (c > 0) lbase[t] = atomicAdd(&bucketCursor[t], c);
  }
  __syncthreads();
  for (int i = t; i < 4096; i += 256) {
    int e = e0 + i;
    if (e < nEdges) {
      int d = dst[e];
      int b = d >> BSHIFT;
      int lp = atomicAdd(&loff[b], 1);
      pairs[lbase[b] + lp] = ((unsigned)src[e] << BSHIFT) | ((unsigned)d & 511u);
    }
  }
}

// One block per bucket: count degrees in LDS, scan in LDS, emit rowStart,
// then single-writer place into csrSrc.
__global__ __launch_bounds__(256) void local_fill_kernel(
    const unsigned* __restrict__ pairs, const int* __restrict__ buckOff,
    int* __restrict__ rowStart, int* __restrict__ csrSrc,
    int nNodes, int nBuck) {
  __shared__ int sData[BCAP];           // 48 KB
  __shared__ int lcnt[1 << BSHIFT];     // 2 KB: counts, then running cursors
  __shared__ int sSum[256];             // 1 KB scan temp
  int b = blockIdx.x;
  int node0 = b << BSHIFT;
  int base = buckOff[b];
  int end = buckOff[b + 1];
  int cnt = end - base;
  int t = threadIdx.x;

  lcnt[t] = 0;
  lcnt[t + 256] = 0;
  __syncthreads();

  for (int i = base + t; i < end; i += 256)
    atomicAdd(&lcnt[pairs[i] & 511u], 1);
  __syncthreads();

  int c0 = lcnt[2 * t];
  int c1 = lcnt[2 * t + 1];
  int local = c0 + c1;
  sSum[t] = local;
  __syncthreads();
  for (int off = 1; off < 256; off <<= 1) {
    int v = (t >= off) ? sSum[t - off] : 0;
    __syncthreads();
    sSum[t] += v;
    __syncthreads();
  }
  int excl = sSum[t] - local;
  __syncthreads();
  lcnt[2 * t] = excl;
  lcnt[2 * t + 1] = excl + c0;
  int n0 = node0 + 2 * t;
  int n1 = n0 + 1;
  if (n0 < nNodes) rowStart[n0] = base + excl;
  if (n1 < nNodes) rowStart[n1] = base + excl + c0;
  if (b == nBuck - 1 && t == 255) rowStart[nNodes] = end;
  __syncthreads();

  if (cnt <= BCAP) {
    for (int i = base + t; i < end; i += 256) {
      unsigned p = pairs[i];
      int lp = atomicAdd(&lcnt[p & 511u], 1);
      sData[lp] = (int)(p >> BSHIFT);
    }
    __syncthreads();
    for (int i = t; i < cnt; i += 256)
      csrSrc[base + i] = sData[i];
  } else {
    for (int i = base + t; i < end; i += 256) {
      unsigned p = pairs[i];
      int lp = atomicAdd(&lcnt[p & 511u], 1);
      csrSrc[base + lp] = (int)(p >> BSHIFT);
    }
  }
}

// ================= prep: fp32 -> fp16 (node-major) =================
__global__ __launch_bounds__(256) void convert_feat_kernel(
    const float* __restrict__ f, unsigned short* __restrict__ o, int nElems) {
  int i = (blockIdx.x * 256 + threadIdx.x) * 4;
  if (i + 3 < nElems) {
    float4 v = *((const float4*)(f + i));
    unsigned a = (unsigned)f2h(v.x) | ((unsigned)f2h(v.y) << 16);
    unsigned b = (unsigned)f2h(v.z) | ((unsigned)f2h(v.w) << 16);
    *((uint2*)(o + i)) = make_uint2(a, b);
  } else {
    for (int j = i; j < nElems; ++j) o[j] = f2h(f[j]);
  }
}

// Wt[l][n][k] fp16, k<128 from Wl[k][n], k>=128 from Wr[k-128][n]
__global__ __launch_bounds__(256) void pack_weights_kernel(
    const float* __restrict__ Wl0, const float* __restrict__ Wr0,
    const float* __restrict__ Wl1, const float* __restrict__ Wr1,
    const float* __restrict__ Wl2, const float* __restrict__ Wr2,
    unsigned short* __restrict__ Wt) {
  int t = blockIdx.x * 256 + threadIdx.x;
  if (t >= 3 * 128 * 256) return;
  int l = t >> 15;
  int rem = t & 32767;
  int n = rem >> 8;
  int k = rem & 255;
  const float* Wl = (l == 0) ? Wl0 : (l == 1) ? Wl1 : Wl2;
  const float* Wr = (l == 0) ? Wr0 : (l == 1) ? Wr1 : Wr2;
  float v = (k < 128) ? Wl[k * D + n] : Wr[(k - 128) * D + n];
  Wt[t] = f2h(v);
}

// ================= gather segment-max on fp16 rows (node-major) ===========
// One wave per node (max TLP; latency-bound phase). 16 B/lane: 16 lanes
// cover the 256 B row; four 16-lane quarters take different edges.
// Unrolled to 16 edges/iter = 4 independent idx+granule chains per lane.
__global__ __launch_bounds__(256) void gather_max_f16_kernel(
    const uint4* __restrict__ x8, const int* __restrict__ rowStart,
    const int* __restrict__ csrSrc, uint4* __restrict__ agg8, int nNodes) {
  int n = blockIdx.x * 4 + (threadIdx.x >> 6);
  if (n >= nNodes) return;
  int lane = threadIdx.x & 63;
  int q = lane >> 4;        // quarter: which edge of a group of 4
  int l16 = lane & 15;      // 16-byte segment within the row
  int e0 = rowStart[n], e1 = rowStart[n + 1];
  unsigned m0 = 0xFC00FC00u, m1 = 0xFC00FC00u,  // packed fp16 -inf
           m2 = 0xFC00FC00u, m3 = 0xFC00FC00u;
  int e = e0;
  for (; e + 15 < e1; e += 16) {    // 4 independent chains
    int sa = csrSrc[e + q];
    int sb = csrSrc[e + 4 + q];
    int sc = csrSrc[e + 8 + q];
    int sd = csrSrc[e + 12 + q];
    uint4 va = x8[(size_t)sa * 16 + l16];
    uint4 vb = x8[(size_t)sb * 16 + l16];
    uint4 vc = x8[(size_t)sc * 16 + l16];
    uint4 vd = x8[(size_t)sd * 16 + l16];
    m0 = pkmax(m0, pkmax(pkmax(va.x, vb.x), pkmax(vc.x, vd.x)));
    m1 = pkmax(m1, pkmax(pkmax(va.y, vb.y), pkmax(vc.y, vd.y)));
    m2 = pkmax(m2, pkmax(pkmax(va.z, vb.z), pkmax(vc.z, vd.z)));
    m3 = pkmax(m3, pkmax(pkmax(va.w, vb.w), pkmax(vc.w, vd.w)));
  }
  if (e + 7 < e1) {                 // 2 chains
    int sa = csrSrc[e + q];
    int sb = csrSrc[e + 4 + q];
    uint4 va = x8[(size_t)sa * 16 + l16];
    uint4 vb = x8[(size_t)sb * 16 + l16];
    m0 = pkmax(m0, pkmax(va.x, vb.x));
    m1 = pkmax(m1, pkmax(va.y, vb.y));
    m2 = pkmax(m2, pkmax(va.z, vb.z));
    m3 = pkmax(m3, pkmax(va.w, vb.w));
    e += 8;
  }
  if (e + 3 < e1) {
    int sa = csrSrc[e + q];
    uint4 va = x8[(size_t)sa * 16 + l16];
    m0 = pkmax(m0, va.x); m1 = pkmax(m1, va.y);
    m2 = pkmax(m2, va.z); m3 = pkmax(m3, va.w);
    e += 4;
  }
  for (; e < e1; ++e) {     // <4 leftover: all quarters read same row
    int sa = csrSrc[e];
    uint4 va = x8[(size_t)sa * 16 + l16];
    m0 = pkmax(m0, va.x); m1 = pkmax(m1, va.y);
    m2 = pkmax(m2, va.z); m3 = pkmax(m3, va.w);
  }
  // combine the four quarters (packed shuffles)
  m0 = pkmax(m0, (unsigned)__shfl_xor((int)m0, 16, 64));
  m1 = pkmax(m1, (unsigned)__shfl_xor((int)m1, 16, 64));
  m2 = pkmax(m2, (unsigned)__shfl_xor((int)m2, 16, 64));
  m3 = pkmax(m3, (unsigned)__shfl_xor((int)m3, 16, 64));
  m0 = pkmax(m0, (unsigned)__shfl_xor((int)m0, 32, 64));
  m1 = pkmax(m1, (unsigned)__shfl_xor((int)m1, 32, 64));
  m2 = pkmax(m2, (unsigned)__shfl_xor((int)m2, 32, 64));
  m3 = pkmax(m3, (unsigned)__shfl_xor((int)m3, 32, 64));
  uint4 r = make_uint4(0u, 0u, 0u, 0u);  // isolated node -> +0.0
  if (e0 != e1) r = make_uint4(m0, m1, m2, m3);
  if (q == 0) agg8[(size_t)n * 16 + l16] = r;
}

// ====== MFMA layer: 64-row tile, LDS-staged coalesced fp16 stores ======
// Dropout threefry mask is HOISTED above the barrier/MFMA phase: it depends
// only on indices, so its ~2.2K VALU instrs execute in the shadow of the
// staging loads' waitcnt + MFMA latency instead of after acc is live.
#define PA 280
#define TROWS 64

__global__ __launch_bounds__(256, 2) void fused_mfma_kernel(
    const unsigned short* __restrict__ agghf, unsigned short* __restrict__ xhf,
    const unsigned short* __restrict__ Wt, const float* __restrict__ bias,
    float* __restrict__ outF, int nRows, int mode, unsigned kk0, unsigned kk1) {
  __shared__ unsigned short sA[TROWS * PA];   // 35.8 KB

  const int tid = threadIdx.x;
  const int row0 = blockIdx.x * TROWS;
  const int wv = tid >> 6, lane = tid & 63;
  const int quad = lane >> 4, m16 = lane & 15;
  const int nbase = wv * 32;

  // ---- stage A: 64 rows x 256 k (agg cols 0..127, self cols 128..255) ----
#pragma unroll
  for (int i = 0; i < 8; ++i) {
    int idx = i * 256 + tid;
    int r = idx >> 5;
    int seg = idx & 31;
    uint4 v = make_uint4(0, 0, 0, 0);
    if (row0 + r < nRows) {
      if (seg < 16) v = ((const uint4*)(agghf + (size_t)(row0 + r) * D))[seg];
      else          v = ((const uint4*)(xhf  + (size_t)(row0 + r) * D))[seg - 16];
    }
    *((uint4*)(sA + r * PA + seg * 8)) = v;
  }

  // ---- B fragments (L2-resident weights) ----
  half8 bfr[2][4][2];
#pragma unroll
  for (int kc = 0; kc < 2; ++kc)
#pragma unroll
    for (int ks = 0; ks < 4; ++ks)
#pragma unroll
      for (int j = 0; j < 2; ++j)
        bfr[kc][ks][j] = *((const half8*)(
            Wt + (size_t)(nbase + j * 16 + m16) * 256 + kc * 128 + ks * 32 + quad * 8));

  // ---- dropout mask precompute (index-only; hides under load latency) ----
  unsigned dmask = 0u;
  if (mode < 2) {
#pragma unroll
    for (int j = 0; j < 2; ++j) {
      int col = nbase + j * 16 + m16;
#pragma unroll
      for (int i = 0; i < 4; ++i) {
#pragma unroll
        for (int reg = 0; reg < 4; ++reg) {
          int r = row0 + i * 16 + quad * 4 + reg;
          unsigned jj = (unsigned)r * D + col;
          unsigned y0, y1;
          threefry2x32(kk0, kk1, 0u, jj, y0, y1);
          float u = __uint_as_float((((y0 ^ y1) >> 9)) | 0x3F800000u) - 1.0f;
          if (u < 0.8f) dmask |= (1u << (j * 16 + i * 4 + reg));
        }
      }
    }
  }

  floatx4 acc[4][2];
#pragma unroll
  for (int i = 0; i < 4; ++i)
#pragma unroll
    for (int j = 0; j < 2; ++j) acc[i][j] = (floatx4)(0.0f);

  __syncthreads();

#pragma unroll
  for (int kc = 0; kc < 2; ++kc)
#pragma unroll
    for (int ks = 0; ks < 4; ++ks) {
      int kA = kc * 128 + ks * 32 + quad * 8;
#pragma unroll
      for (int i = 0; i < 4; ++i) {
        half8 a = *((const half8*)(sA + (m16 + 16 * i) * PA + kA));
        acc[i][0] = __builtin_amdgcn_mfma_f32_16x16x32_f16(a, bfr[kc][ks][0], acc[i][0], 0, 0, 0);
        acc[i][1] = __builtin_amdgcn_mfma_f32_16x16x32_f16(a, bfr[kc][ks][1], acc[i][1], 0, 0, 0);
      }
    }

  if (mode < 2) {
    // epilogue: ELU + masked dropout, stage fp16 tile in LDS, coalesced store
    __syncthreads();   // all MFMA reads of sA done before overwrite
#pragma unroll
    for (int j = 0; j < 2; ++j) {
      int col = nbase + j * 16 + m16;
      float bc = bias[col];
#pragma unroll
      for (int i = 0; i < 4; ++i) {
#pragma unroll
        for (int reg = 0; reg < 4; ++reg) {
          int r = i * 16 + quad * 4 + reg;
          if (row0 + r >= nRows) continue;
          float v = acc[i][j][reg] + bc;
          v = (v > 0.0f) ? v : (__expf(v) - 1.0f);   // ELU via hw exp
          v = ((dmask >> (j * 16 + i * 4 + reg)) & 1u) ? v * 1.25f : 0.0f;
          sA[r * PA + col] = f2h(v);
        }
      }
    }
    __syncthreads();
#pragma unroll
    for (int i = 0; i < 4; ++i) {
      int idx = i * 256 + tid;
      int r = idx >> 4;
      int seg = idx & 15;
      if (row0 + r < nRows)
        ((uint4*)xhf)[(size_t)(row0 + r) * 16 + seg] =
            *((const uint4*)(sA + r * PA + seg * 8));
    }
  } else {
    // final layer: fp32 out, 64 B-contiguous stores per quad
#pragma unroll
    for (int j = 0; j < 2; ++j) {
      int col = nbase + j * 16 + m16;
      float bc = bias[col];
#pragma unroll
      for (int i = 0; i < 4; ++i) {
#pragma unroll
        for (int reg = 0; reg < 4; ++reg) {
          int r = row0 + i * 16 + quad * 4 + reg;
          if (r >= nRows) continue;
          outF[(size_t)r * D + col] = acc[i][j][reg] + bc;
        }
      }
    }
  }
}

extern "C" void kernel_launch(void* const* d_in, const int* in_sizes, int n_in,
                              void* d_out, int out_size, void* d_ws, size_t ws_size,
                              hipStream_t stream) {
  const float* feat = (const float*)d_in[0];
  const int* ei = (const int*)d_in[1];
  const float* Wl0 = (const float*)d_in[2];
  const float* Wr0 = (const float*)d_in[3];
  const float* b0 = (const float*)d_in[4];
  const float* Wl1 = (const float*)d_in[5];
  const float* Wr1 = (const float*)d_in[6];
  const float* b1 = (const float*)d_in[7];
  const float* Wl2 = (const float*)d_in[8];
  const float* Wr2 = (const float*)d_in[9];
  const float* b2 = (const float*)d_in[10];

  const int N = in_sizes[0] / D;   // 100000
  const int E = in_sizes[1] / 2;   // 1600000
  const int* src = ei;
  const int* dst = ei + E;

  // ---- workspace ----
  const size_t hfBytes = (size_t)N * D * 2;   // 25.6 MB
  char* wsp = (char*)d_ws;
  size_t off = 0;
  unsigned short* xhf   = (unsigned short*)(wsp + off); off += hfBytes;
  unsigned short* agghf = (unsigned short*)(wsp + off); off += hfBytes;
  unsigned short* Wt    = (unsigned short*)(wsp + off); off += ((size_t)3 * 128 * 256 * 2 + 511) & ~511ull;
  int* rowStart     = (int*)(wsp + off); off += ((size_t)(N + 1) * 4 + 511) & ~511ull;
  int* bucketTotal  = (int*)(wsp + off); off += 2048;
  int* buckOff      = (int*)(wsp + off); off += 2048;
  int* bucketCursor = (int*)(wsp + off); off += 2048;
  int* csrSrc    = (int*)(wsp + off); off += (size_t)E * 4;
  unsigned* pairs = (unsigned*)(wsp + off); off += (size_t)E * 4;  // 6.4 MB

  const int nBuck = (N + (1 << BSHIFT) - 1) >> BSHIFT;    // 196

  // ---- JAX partitionable threefry keys on host ----
  unsigned k1a, k1b, k2a, k2b;
  threefry2x32(0u, 42u, 0u, 0u, k1a, k1b);
  threefry2x32(0u, 42u, 0u, 1u, k2a, k2b);

  // ---- CSR build ----
  hipMemsetAsync(bucketTotal, 0, 1024, stream);
  bucket_count_kernel<<<(E + 4095) / 4096, 256, 0, stream>>>(dst, bucketTotal, E);
  scan_buckets_kernel<<<1, 256, 0, stream>>>(bucketTotal, buckOff, bucketCursor, nBuck);
  bucket_scatter_kernel<<<(E + 4095) / 4096, 256, 0, stream>>>(src, dst, bucketCursor, pairs, E, nBuck);
  local_fill_kernel<<<nBuck, 256, 0, stream>>>(pairs, buckOff, rowStart, csrSrc, N, nBuck);

  // ---- prep fp16 ----
  convert_feat_kernel<<<(N * D / 4 + 255) / 256, 256, 0, stream>>>(feat, xhf, N * D);
  pack_weights_kernel<<<(3 * 128 * 256 + 255) / 256, 256, 0, stream>>>(
      Wl0, Wr0, Wl1, Wr1, Wl2, Wr2, Wt);

  dim3 blk(256);
  dim3 grdMax((N + 3) / 4);
  dim3 grdGemm((N + TROWS - 1) / TROWS);
  float* outF = (float*)d_out;

  // ---- layer 0 ----
  gather_max_f16_kernel<<<grdMax, blk, 0, stream>>>((const uint4*)xhf, rowStart, csrSrc, (uint4*)agghf, N);
  fused_mfma_kernel<<<grdGemm, blk, 0, stream>>>(agghf, xhf, Wt, b0, outF, N, 0, k1a, k1b);

  // ---- layer 1 ----
  gather_max_f16_kernel<<<grdMax, blk, 0, stream>>>((const uint4*)xhf, rowStart, csrSrc, (uint4*)agghf, N);
  fused_mfma_kernel<<<grdGemm, blk, 0, stream>>>(agghf, xhf, Wt + 32768, b1, outF, N, 1, k2a, k2b);

  // ---- layer 2 (fp32 out) ----
  gather_max_f16_kernel<<<grdMax, blk, 0, stream>>>((const uint4*)xhf, rowStart, csrSrc, (uint4*)agghf, N);
  fused_mfma_kernel<<<grdGemm, blk, 0, stream>>>(agghf, xhf, Wt + 65536, b2, outF, N, 2, 0u, 0u);
}

// Round 10
// 482.132 us; speedup vs baseline: 1.0024x; 1.0024x over previous
//
#include <hip/hip_runtime.h>
#include <math.h>

#define D 128
#define BSHIFT 9              // bucket = 512 nodes
#define BCAP 12288            // LDS staging capacity (edges) per bucket

typedef __attribute__((ext_vector_type(8))) _Float16 half8;
typedef __attribute__((ext_vector_type(4))) float floatx4;

// ---------------- threefry2x32 (JAX-compatible, 20 rounds) ----------------
__host__ __device__ __forceinline__ unsigned rotl32(unsigned v, int r) {
  return (v << r) | (v >> (32 - r));
}

__host__ __device__ __forceinline__ void threefry2x32(unsigned k0, unsigned k1,
                                                      unsigned x0, unsigned x1,
                                                      unsigned &o0, unsigned &o1) {
  unsigned ks2 = k0 ^ k1 ^ 0x1BD11BDAu;
  unsigned v0 = x0 + k0;
  unsigned v1 = x1 + k1;
  v0 += v1; v1 = rotl32(v1, 13); v1 ^= v0;
  v0 += v1; v1 = rotl32(v1, 15); v1 ^= v0;
  v0 += v1; v1 = rotl32(v1, 26); v1 ^= v0;
  v0 += v1; v1 = rotl32(v1, 6);  v1 ^= v0;
  v0 += k1; v1 += ks2 + 1u;
  v0 += v1; v1 = rotl32(v1, 17); v1 ^= v0;
  v0 += v1; v1 = rotl32(v1, 29); v1 ^= v0;
  v0 += v1; v1 = rotl32(v1, 16); v1 ^= v0;
  v0 += v1; v1 = rotl32(v1, 24); v1 ^= v0;
  v0 += ks2; v1 += k0 + 2u;
  v0 += v1; v1 = rotl32(v1, 13); v1 ^= v0;
  v0 += v1; v1 = rotl32(v1, 15); v1 ^= v0;
  v0 += v1; v1 = rotl32(v1, 26); v1 ^= v0;
  v0 += v1; v1 = rotl32(v1, 6);  v1 ^= v0;
  v0 += k0; v1 += k1 + 3u;
  v0 += v1; v1 = rotl32(v1, 17); v1 ^= v0;
  v0 += v1; v1 = rotl32(v1, 29); v1 ^= v0;
  v0 += v1; v1 = rotl32(v1, 16); v1 ^= v0;
  v0 += v1; v1 = rotl32(v1, 24); v1 ^= v0;
  v0 += k1; v1 += ks2 + 4u;
  v0 += v1; v1 = rotl32(v1, 13); v1 ^= v0;
  v0 += v1; v1 = rotl32(v1, 15); v1 ^= v0;
  v0 += v1; v1 = rotl32(v1, 26); v1 ^= v0;
  v0 += v1; v1 = rotl32(v1, 6);  v1 ^= v0;
  v0 += ks2; v1 += k0 + 5u;
  o0 = v0; o1 = v1;
}

// float -> fp16 bits (RNE via v_cvt_f16_f32)
__device__ __forceinline__ unsigned short f2h(float f) {
  _Float16 h = (_Float16)f;
  return *(unsigned short*)&h;
}

// packed fp16 max (VOP3P, 1 instr for 2 elements)
__device__ __forceinline__ unsigned pkmax(unsigned a, unsigned b) {
  unsigned r;
  asm("v_pk_max_f16 %0, %1, %2" : "=v"(r) : "v"(a), "v"(b));
  return r;
}

// ===== fused prep: convert (fp32->fp16) + pack weights + bucket count =====
// Three independent jobs partitioned by blockIdx range -> one dispatch,
// overlapped memory streams.
__global__ __launch_bounds__(256) void prep_kernel(
    const float* __restrict__ feat, unsigned short* __restrict__ xhf,
    const float* __restrict__ Wl0, const float* __restrict__ Wr0,
    const float* __restrict__ Wl1, const float* __restrict__ Wr1,
    const float* __restrict__ Wl2, const float* __restrict__ Wr2,
    unsigned short* __restrict__ Wt,
    const int* __restrict__ dst, int* __restrict__ bucketTotal,
    int nElems, int nEdges, int nConv, int nPack) {
  int b = blockIdx.x;
  int t = threadIdx.x;
  if (b < nConv) {
    // ---- convert features ----
    int i = (b * 256 + t) * 4;
    if (i + 3 < nElems) {
      float4 v = *((const float4*)(feat + i));
      unsigned a = (unsigned)f2h(v.x) | ((unsigned)f2h(v.y) << 16);
      unsigned c = (unsigned)f2h(v.z) | ((unsigned)f2h(v.w) << 16);
      *((uint2*)(xhf + i)) = make_uint2(a, c);
    } else {
      for (int j = i; j < nElems; ++j) xhf[j] = f2h(feat[j]);
    }
  } else if (b < nConv + nPack) {
    // ---- pack weights: Wt[l][n][k] ----
    int w = (b - nConv) * 256 + t;
    if (w < 3 * 128 * 256) {
      int l = w >> 15;
      int rem = w & 32767;
      int n = rem >> 8;
      int k = rem & 255;
      const float* Wl = (l == 0) ? Wl0 : (l == 1) ? Wl1 : Wl2;
      const float* Wr = (l == 0) ? Wr0 : (l == 1) ? Wr1 : Wr2;
      float v = (k < 128) ? Wl[k * D + n] : Wr[(k - 128) * D + n];
      Wt[w] = f2h(v);
    }
  } else {
    // ---- bucket histogram (LDS-privatized) ----
    __shared__ int lc[256];
    lc[t] = 0;
    __syncthreads();
    int e0 = (b - nConv - nPack) * 4096;
    for (int i = t; i < 4096; i += 256) {
      int e = e0 + i;
      if (e < nEdges) atomicAdd(&lc[dst[e] >> BSHIFT], 1);
    }
    __syncthreads();
    int c = lc[t];
    if (c > 0) atomicAdd(&bucketTotal[t], c);
  }
}

__global__ __launch_bounds__(256) void scan_buckets_kernel(
    const int* __restrict__ bucketTotal, int* __restrict__ buckOff,
    int* __restrict__ bucketCursor, int nBuck) {
  __shared__ int s[256];
  int t = threadIdx.x;
  int v = (t < nBuck) ? bucketTotal[t] : 0;
  s[t] = v;
  __syncthreads();
  for (int off = 1; off < 256; off <<= 1) {
    int u = (t >= off) ? s[t - off] : 0;
    __syncthreads();
    s[t] += u;
    __syncthreads();
  }
  int excl = s[t] - v;
  if (t < nBuck) {
    buckOff[t] = excl;
    bucketCursor[t] = excl;
  } else if (t == nBuck) {
    buckOff[t] = s[255];  // total edge count
  }
}

// pairs entry packed: (src << 9) | (dst & 511)  — src < 2^17, fits 26 bits.
__global__ __launch_bounds__(256) void bucket_scatter_kernel(
    const int* __restrict__ src, const int* __restrict__ dst,
    int* __restrict__ bucketCursor, unsigned* __restrict__ pairs,
    int nEdges, int nBuck) {
  __shared__ int lcount[256];
  __shared__ int lbase[256];
  __shared__ int loff[256];
  int t = threadIdx.x;
  lcount[t] = 0; loff[t] = 0;
  __syncthreads();
  int e0 = blockIdx.x * 4096;
  for (int i = t; i < 4096; i += 256) {
    int e = e0 + i;
    if (e < nEdges) atomicAdd(&lcount[dst[e] >> BSHIFT], 1);
  }
  __syncthreads();
  if (t < nBuck) {
    int c = lcount[t];
    if (c > 0) lbase[t] = atomicAdd(&bucketCursor[t], c);
  }
  __syncthreads();
  for (int i = t; i < 4096; i += 256) {
    int e = e0 + i;
    if (e < nEdges) {
      int d = dst[e];
      int b = d >> BSHIFT;
      int lp = atomicAdd(&loff[b], 1);
      pairs[lbase[b] + lp] = ((unsigned)src[e] << BSHIFT) | ((unsigned)d & 511u);
    }
  }
}

// One block per bucket: count degrees in LDS, scan in LDS, emit rowStart,
// then single-writer place into csrSrc.
__global__ __launch_bounds__(256) void local_fill_kernel(
    const unsigned* __restrict__ pairs, const int* __restrict__ buckOff,
    int* __restrict__ rowStart, int* __restrict__ csrSrc,
    int nNodes, int nBuck) {
  __shared__ int sData[BCAP];           // 48 KB
  __shared__ int lcnt[1 << BSHIFT];     // 2 KB: counts, then running cursors
  __shared__ int sSum[256];             // 1 KB scan temp
  int b = blockIdx.x;
  int node0 = b << BSHIFT;
  int base = buckOff[b];
  int end = buckOff[b + 1];
  int cnt = end - base;
  int t = threadIdx.x;

  lcnt[t] = 0;
  lcnt[t + 256] = 0;
  __syncthreads();

  for (int i = base + t; i < end; i += 256)
    atomicAdd(&lcnt[pairs[i] & 511u], 1);
  __syncthreads();

  int c0 = lcnt[2 * t];
  int c1 = lcnt[2 * t + 1];
  int local = c0 + c1;
  sSum[t] = local;
  __syncthreads();
  for (int off = 1; off < 256; off <<= 1) {
    int v = (t >= off) ? sSum[t - off] : 0;
    __syncthreads();
    sSum[t] += v;
    __syncthreads();
  }
  int excl = sSum[t] - local;
  __syncthreads();
  lcnt[2 * t] = excl;
  lcnt[2 * t + 1] = excl + c0;
  int n0 = node0 + 2 * t;
  int n1 = n0 + 1;
  if (n0 < nNodes) rowStart[n0] = base + excl;
  if (n1 < nNodes) rowStart[n1] = base + excl + c0;
  if (b == nBuck - 1 && t == 255) rowStart[nNodes] = end;
  __syncthreads();

  if (cnt <= BCAP) {
    for (int i = base + t; i < end; i += 256) {
      unsigned p = pairs[i];
      int lp = atomicAdd(&lcnt[p & 511u], 1);
      sData[lp] = (int)(p >> BSHIFT);
    }
    __syncthreads();
    for (int i = t; i < cnt; i += 256)
      csrSrc[base + i] = sData[i];
  } else {
    for (int i = base + t; i < end; i += 256) {
      unsigned p = pairs[i];
      int lp = atomicAdd(&lcnt[p & 511u], 1);
      csrSrc[base + lp] = (int)(p >> BSHIFT);
    }
  }
}

// ================= gather segment-max on fp16 rows (node-major) ===========
// One wave per node (max TLP; latency-bound phase). 16 B/lane: 16 lanes
// cover the 256 B row; four 16-lane quarters take different edges.
// Unrolled to 16 edges/iter = 4 independent idx+granule chains per lane.
__global__ __launch_bounds__(256) void gather_max_f16_kernel(
    const uint4* __restrict__ x8, const int* __restrict__ rowStart,
    const int* __restrict__ csrSrc, uint4* __restrict__ agg8, int nNodes) {
  int n = blockIdx.x * 4 + (threadIdx.x >> 6);
  if (n >= nNodes) return;
  int lane = threadIdx.x & 63;
  int q = lane >> 4;        // quarter: which edge of a group of 4
  int l16 = lane & 15;      // 16-byte segment within the row
  int e0 = rowStart[n], e1 = rowStart[n + 1];
  unsigned m0 = 0xFC00FC00u, m1 = 0xFC00FC00u,  // packed fp16 -inf
           m2 = 0xFC00FC00u, m3 = 0xFC00FC00u;
  int e = e0;
  for (; e + 15 < e1; e += 16) {    // 4 independent chains
    int sa = csrSrc[e + q];
    int sb = csrSrc[e + 4 + q];
    int sc = csrSrc[e + 8 + q];
    int sd = csrSrc[e + 12 + q];
    uint4 va = x8[(size_t)sa * 16 + l16];
    uint4 vb = x8[(size_t)sb * 16 + l16];
    uint4 vc = x8[(size_t)sc * 16 + l16];
    uint4 vd = x8[(size_t)sd * 16 + l16];
    m0 = pkmax(m0, pkmax(pkmax(va.x, vb.x), pkmax(vc.x, vd.x)));
    m1 = pkmax(m1, pkmax(pkmax(va.y, vb.y), pkmax(vc.y, vd.y)));
    m2 = pkmax(m2, pkmax(pkmax(va.z, vb.z), pkmax(vc.z, vd.z)));
    m3 = pkmax(m3, pkmax(pkmax(va.w, vb.w), pkmax(vc.w, vd.w)));
  }
  if (e + 7 < e1) {                 // 2 chains
    int sa = csrSrc[e + q];
    int sb = csrSrc[e + 4 + q];
    uint4 va = x8[(size_t)sa * 16 + l16];
    uint4 vb = x8[(size_t)sb * 16 + l16];
    m0 = pkmax(m0, pkmax(va.x, vb.x));
    m1 = pkmax(m1, pkmax(va.y, vb.y));
    m2 = pkmax(m2, pkmax(va.z, vb.z));
    m3 = pkmax(m3, pkmax(va.w, vb.w));
    e += 8;
  }
  if (e + 3 < e1) {
    int sa = csrSrc[e + q];
    uint4 va = x8[(size_t)sa * 16 + l16];
    m0 = pkmax(m0, va.x); m1 = pkmax(m1, va.y);
    m2 = pkmax(m2, va.z); m3 = pkmax(m3, va.w);
    e += 4;
  }
  for (; e < e1; ++e) {     // <4 leftover: all quarters read same row
    int sa = csrSrc[e];
    uint4 va = x8[(size_t)sa * 16 + l16];
    m0 = pkmax(m0, va.x); m1 = pkmax(m1, va.y);
    m2 = pkmax(m2, va.z); m3 = pkmax(m3, va.w);
  }
  // combine the four quarters (packed shuffles)
  m0 = pkmax(m0, (unsigned)__shfl_xor((int)m0, 16, 64));
  m1 = pkmax(m1, (unsigned)__shfl_xor((int)m1, 16, 64));
  m2 = pkmax(m2, (unsigned)__shfl_xor((int)m2, 16, 64));
  m3 = pkmax(m3, (unsigned)__shfl_xor((int)m3, 16, 64));
  m0 = pkmax(m0, (unsigned)__shfl_xor((int)m0, 32, 64));
  m1 = pkmax(m1, (unsigned)__shfl_xor((int)m1, 32, 64));
  m2 = pkmax(m2, (unsigned)__shfl_xor((int)m2, 32, 64));
  m3 = pkmax(m3, (unsigned)__shfl_xor((int)m3, 32, 64));
  uint4 r = make_uint4(0u, 0u, 0u, 0u);  // isolated node -> +0.0
  if (e0 != e1) r = make_uint4(m0, m1, m2, m3);
  if (q == 0) agg8[(size_t)n * 16 + l16] = r;
}

// ====== MFMA layer: 48-row tile (26.9 KB LDS -> 5 blocks/CU, 62% waves) ====
// Dropout threefry mask hoisted above the barrier/MFMA phase (hides under
// staging-load latency). LDS-staged coalesced fp16 stores.
#define PA 280
#define TROWS 48

__global__ __launch_bounds__(256, 5) void fused_mfma_kernel(
    const unsigned short* __restrict__ agghf, unsigned short* __restrict__ xhf,
    const unsigned short* __restrict__ Wt, const float* __restrict__ bias,
    float* __restrict__ outF, int nRows, int mode, unsigned kk0, unsigned kk1) {
  __shared__ unsigned short sA[TROWS * PA];   // 26.9 KB

  const int tid = threadIdx.x;
  const int row0 = blockIdx.x * TROWS;
  const int wv = tid >> 6, lane = tid & 63;
  const int quad = lane >> 4, m16 = lane & 15;
  const int nbase = wv * 32;

  // ---- stage A: 48 rows x 256 k (agg cols 0..127, self cols 128..255) ----
#pragma unroll
  for (int i = 0; i < 6; ++i) {
    int idx = i * 256 + tid;        // [0,1536)
    int r = idx >> 5;
    int seg = idx & 31;
    uint4 v = make_uint4(0, 0, 0, 0);
    if (row0 + r < nRows) {
      if (seg < 16) v = ((const uint4*)(agghf + (size_t)(row0 + r) * D))[seg];
      else          v = ((const uint4*)(xhf  + (size_t)(row0 + r) * D))[seg - 16];
    }
    *((uint4*)(sA + r * PA + seg * 8)) = v;
  }

  // ---- B fragments (L2-resident weights) ----
  half8 bfr[2][4][2];
#pragma unroll
  for (int kc = 0; kc < 2; ++kc)
#pragma unroll
    for (int ks = 0; ks < 4; ++ks)
#pragma unroll
      for (int j = 0; j < 2; ++j)
        bfr[kc][ks][j] = *((const half8*)(
            Wt + (size_t)(nbase + j * 16 + m16) * 256 + kc * 128 + ks * 32 + quad * 8));

  // ---- dropout mask precompute (index-only; hides under load latency) ----
  unsigned dmask = 0u;
  if (mode < 2) {
#pragma unroll
    for (int j = 0; j < 2; ++j) {
      int col = nbase + j * 16 + m16;
#pragma unroll
      for (int i = 0; i < 3; ++i) {
#pragma unroll
        for (int reg = 0; reg < 4; ++reg) {
          int r = row0 + i * 16 + quad * 4 + reg;
          unsigned jj = (unsigned)r * D + col;
          unsigned y0, y1;
          threefry2x32(kk0, kk1, 0u, jj, y0, y1);
          float u = __uint_as_float((((y0 ^ y1) >> 9)) | 0x3F800000u) - 1.0f;
          if (u < 0.8f) dmask |= (1u << (j * 12 + i * 4 + reg));
        }
      }
    }
  }

  floatx4 acc[3][2];
#pragma unroll
  for (int i = 0; i < 3; ++i)
#pragma unroll
    for (int j = 0; j < 2; ++j) acc[i][j] = (floatx4)(0.0f);

  __syncthreads();

#pragma unroll
  for (int kc = 0; kc < 2; ++kc)
#pragma unroll
    for (int ks = 0; ks < 4; ++ks) {
      int kA = kc * 128 + ks * 32 + quad * 8;
#pragma unroll
      for (int i = 0; i < 3; ++i) {
        half8 a = *((const half8*)(sA + (m16 + 16 * i) * PA + kA));
        acc[i][0] = __builtin_amdgcn_mfma_f32_16x16x32_f16(a, bfr[kc][ks][0], acc[i][0], 0, 0, 0);
        acc[i][1] = __builtin_amdgcn_mfma_f32_16x16x32_f16(a, bfr[kc][ks][1], acc[i][1], 0, 0, 0);
      }
    }

  if (mode < 2) {
    // epilogue: ELU + masked dropout, stage fp16 tile in LDS, coalesced store
    __syncthreads();   // all MFMA reads of sA done before overwrite
#pragma unroll
    for (int j = 0; j < 2; ++j) {
      int col = nbase + j * 16 + m16;
      float bc = bias[col];
#pragma unroll
      for (int i = 0; i < 3; ++i) {
#pragma unroll
        for (int reg = 0; reg < 4; ++reg) {
          int r = i * 16 + quad * 4 + reg;
          if (row0 + r >= nRows) continue;
          float v = acc[i][j][reg] + bc;
          v = (v > 0.0f) ? v : (__expf(v) - 1.0f);   // ELU via hw exp
          v = ((dmask >> (j * 12 + i * 4 + reg)) & 1u) ? v * 1.25f : 0.0f;
          sA[r * PA + col] = f2h(v);
        }
      }
    }
    __syncthreads();
#pragma unroll
    for (int i = 0; i < 3; ++i) {
      int idx = i * 256 + tid;      // [0,768)
      int r = idx >> 4;
      int seg = idx & 15;
      if (row0 + r < nRows)
        ((uint4*)xhf)[(size_t)(row0 + r) * 16 + seg] =
            *((const uint4*)(sA + r * PA + seg * 8));
    }
  } else {
    // final layer: fp32 out, 64 B-contiguous stores per quad
#pragma unroll
    for (int j = 0; j < 2; ++j) {
      int col = nbase + j * 16 + m16;
      float bc = bias[col];
#pragma unroll
      for (int i = 0; i < 3; ++i) {
#pragma unroll
        for (int reg = 0; reg < 4; ++reg) {
          int r = row0 + i * 16 + quad * 4 + reg;
          if (r >= nRows) continue;
          outF[(size_t)r * D + col] = acc[i][j][reg] + bc;
        }
      }
    }
  }
}

extern "C" void kernel_launch(void* const* d_in, const int* in_sizes, int n_in,
                              void* d_out, int out_size, void* d_ws, size_t ws_size,
                              hipStream_t stream) {
  const float* feat = (const float*)d_in[0];
  const int* ei = (const int*)d_in[1];
  const float* Wl0 = (const float*)d_in[2];
  const float* Wr0 = (const float*)d_in[3];
  const float* b0 = (const float*)d_in[4];
  const float* Wl1 = (const float*)d_in[5];
  const float* Wr1 = (const float*)d_in[6];
  const float* b1 = (const float*)d_in[7];
  const float* Wl2 = (const float*)d_in[8];
  const float* Wr2 = (const float*)d_in[9];
  const float* b2 = (const float*)d_in[10];

  const int N = in_sizes[0] / D;   // 100000
  const int E = in_sizes[1] / 2;   // 1600000
  const int* src = ei;
  const int* dst = ei + E;

  // ---- workspace ----
  const size_t hfBytes = (size_t)N * D * 2;   // 25.6 MB
  char* wsp = (char*)d_ws;
  size_t off = 0;
  unsigned short* xhf   = (unsigned short*)(wsp + off); off += hfBytes;
  unsigned short* agghf = (unsigned short*)(wsp + off); off += hfBytes;
  unsigned short* Wt    = (unsigned short*)(wsp + off); off += ((size_t)3 * 128 * 256 * 2 + 511) & ~511ull;
  int* rowStart     = (int*)(wsp + off); off += ((size_t)(N + 1) * 4 + 511) & ~511ull;
  int* bucketTotal  = (int*)(wsp + off); off += 2048;
  int* buckOff      = (int*)(wsp + off); off += 2048;
  int* bucketCursor = (int*)(wsp + off); off += 2048;
  int* csrSrc    = (int*)(wsp + off); off += (size_t)E * 4;
  unsigned* pairs = (unsigned*)(wsp + off); off += (size_t)E * 4;  // 6.4 MB

  const int nBuck = (N + (1 << BSHIFT) - 1) >> BSHIFT;    // 196

  // ---- JAX partitionable threefry keys on host ----
  unsigned k1a, k1b, k2a, k2b;
  threefry2x32(0u, 42u, 0u, 0u, k1a, k1b);
  threefry2x32(0u, 42u, 0u, 1u, k2a, k2b);

  // ---- prep (convert + pack + bucket count, fused) + CSR build ----
  const int nConv = (N * D / 4 + 255) / 256;    // 12500
  const int nPack = (3 * 128 * 256 + 255) / 256; // 384
  const int nCount = (E + 4095) / 4096;          // 391
  hipMemsetAsync(bucketTotal, 0, 1024, stream);
  prep_kernel<<<nConv + nPack + nCount, 256, 0, stream>>>(
      feat, xhf, Wl0, Wr0, Wl1, Wr1, Wl2, Wr2, Wt,
      dst, bucketTotal, N * D, E, nConv, nPack);
  scan_buckets_kernel<<<1, 256, 0, stream>>>(bucketTotal, buckOff, bucketCursor, nBuck);
  bucket_scatter_kernel<<<(E + 4095) / 4096, 256, 0, stream>>>(src, dst, bucketCursor, pairs, E, nBuck);
  local_fill_kernel<<<nBuck, 256, 0, stream>>>(pairs, buckOff, rowStart, csrSrc, N, nBuck);

  dim3 blk(256);
  dim3 grdMax((N + 3) / 4);
  dim3 grdGemm((N + TROWS - 1) / TROWS);
  float* outF = (float*)d_out;

  // ---- layer 0 ----
  gather_max_f16_kernel<<<grdMax, blk, 0, stream>>>((const uint4*)xhf, rowStart, csrSrc, (uint4*)agghf, N);
  fused_mfma_kernel<<<grdGemm, blk, 0, stream>>>(agghf, xhf, Wt, b0, outF, N, 0, k1a, k1b);

  // ---- layer 1 ----
  gather_max_f16_kernel<<<grdMax, blk, 0, stream>>>((const uint4*)xhf, rowStart, csrSrc, (uint4*)agghf, N);
  fused_mfma_kernel<<<grdGemm, blk, 0, stream>>>(agghf, xhf, Wt + 32768, b1, outF, N, 1, k2a, k2b);

  // ---- layer 2 (fp32 out) ----
  gather_max_f16_kernel<<<grdMax, blk, 0, stream>>>((const uint4*)xhf, rowStart, csrSrc, (uint4*)agghf, N);
  fused_mfma_kernel<<<grdGemm, blk, 0, stream>>>(agghf, xhf, Wt + 65536, b2, outF, N, 2, 0u, 0u);
}